// Round 4
// baseline (4452.163 us; speedup 1.0000x reference)
//
#include <hip/hip_runtime.h>
#include <math.h>

#define NN    10000
#define SSS   4
#define LL    8
#define HH    128
#define GG    384
#define NSEQ  40000
#define SUBN  100
#define ORIGF 64

#define MA 8
#define TA 384
#define MB 8

__device__ __forceinline__ float sigmoidf_(float x) { return 1.f / (1.f + __expf(-x)); }
__device__ __forceinline__ float softplusf_(float x) {
  return fmaxf(x, 0.f) + log1pf(__expf(-fabsf(x)));
}

// acc[m] (+)= bias + dot128(W[w0..w0+127], x0 + m*xstride)   (all fp32)
template<int M, bool INIT>
__device__ __forceinline__ void dotsM(const float* __restrict__ W, int w0, float bias,
                                      const float* x0, int xstride, float* acc) {
  if (INIT) {
    #pragma unroll
    for (int m = 0; m < M; ++m) acc[m] = bias;
  }
  #pragma unroll 1
  for (int kc = 0; kc < HH; kc += 8) {
    const float4 wa = *(const float4*)(W + w0 + kc);
    const float4 wb = *(const float4*)(W + w0 + kc + 4);
    #pragma unroll
    for (int m = 0; m < M; ++m) {
      const float* x = x0 + m * xstride + kc;
      const float4 a = *(const float4*)(x);
      const float4 b = *(const float4*)(x + 4);
      float s = acc[m];
      s = fmaf(wa.x, a.x, s); s = fmaf(wa.y, a.y, s);
      s = fmaf(wa.z, a.z, s); s = fmaf(wa.w, a.w, s);
      s = fmaf(wb.x, b.x, s); s = fmaf(wb.y, b.y, s);
      s = fmaf(wb.z, b.z, s); s = fmaf(wb.w, b.w, s);
      acc[m] = s;
    }
  }
}

// ---------------- main kernel: hT for all S*N sequences ----------------
__global__ __launch_bounds__(TA) void k_rum_main(
    const float* __restrict__ hfeat,
    const float* __restrict__ Wih_w, const float* __restrict__ Whh_w,
    const float* __restrict__ bih_w, const float* __restrict__ bhh_w,
    const float* __restrict__ Wih,   const float* __restrict__ Whh,
    const float* __restrict__ bih,   const float* __restrict__ bhh,
    const int* __restrict__ walks,
    float* __restrict__ out)
{
  __shared__ float s_h[MA][HH];
  __shared__ float s_g[MA][GG];
  __shared__ float s_gn[MA][HH];
  __shared__ float s_x[MA][HH];
  __shared__ float s_yw[MA][LL][HH];
  __shared__ int s_wf[MA][LL];
  __shared__ int s_uf[MA][LL];

  const int tid = threadIdx.x;
  const int j = tid;
  const int q0 = blockIdx.x * MA;

  if (tid < MA) {
    const int m = tid;
    const int q = q0 + m;                 // grid is exact: q < NSEQ
    int w[LL];
    #pragma unroll
    for (int l = 0; l < LL; ++l) w[l] = walks[q * LL + l];
    #pragma unroll
    for (int l = 0; l < LL; ++l) {
      int u = l;
      #pragma unroll
      for (int l2 = LL - 1; l2 >= 0; --l2) if (w[l2] == w[l]) u = l2;
      s_wf[m][LL - 1 - l] = w[l];
      s_uf[m][LL - 1 - l] = u;
    }
  }
  for (int idx = tid; idx < MA * HH; idx += TA) ((float*)s_h)[idx] = 0.f;
  __syncthreads();

  // ---- walk GRU (input = one-hot -> column gather of Wih_w) ----
  for (int t = 0; t < LL; ++t) {
    {
      float acc[MA];
      dotsM<MA, true>(Whh_w, j * HH, bhh_w[j], &s_h[0][0], HH, acc);
      #pragma unroll
      for (int m = 0; m < MA; ++m) s_g[m][j] = acc[m];
    }
    __syncthreads();
    for (int idx = tid; idx < MA * HH; idx += TA) {
      const int m = idx / HH, i = idx % HH;
      const int u = s_uf[m][t];
      const float gr = Wih_w[i * LL + u]            + bih_w[i];
      const float gz = Wih_w[(HH + i) * LL + u]     + bih_w[HH + i];
      const float gn = Wih_w[(2 * HH + i) * LL + u] + bih_w[2 * HH + i];
      const float r = sigmoidf_(gr + s_g[m][i]);
      const float z = sigmoidf_(gz + s_g[m][HH + i]);
      const float n = tanhf(gn + r * s_g[m][2 * HH + i]);
      const float hn = (1.f - z) * n + z * s_h[m][i];
      s_h[m][i] = hn;
      s_yw[m][t][i] = hn;
    }
    __syncthreads();
  }

  // ---- main GRU: x_t = [h[walks_f[t]] , y_walk[t]], h0 = h_walk ----
  for (int t = 0; t < LL; ++t) {
    for (int idx = tid; idx < MA * HH; idx += TA) {
      const int m = idx / HH, i = idx % HH;
      s_x[m][i] = hfeat[s_wf[m][t] * HH + i];
    }
    float accg[MA];
    dotsM<MA, true>(Whh, j * HH, bhh[j], &s_h[0][0], HH, accg);
    __syncthreads();
    float acci[MA];
    dotsM<MA, true>(Wih, j * (2 * HH), bih[j], &s_x[0][0], HH, acci);
    dotsM<MA, false>(Wih, j * (2 * HH) + HH, 0.f, &s_yw[0][t][0], LL * HH, acci);
    if (j < 2 * HH) {
      #pragma unroll
      for (int m = 0; m < MA; ++m) s_g[m][j] = accg[m] + acci[m];
    } else {
      #pragma unroll
      for (int m = 0; m < MA; ++m) { s_g[m][j] = accg[m]; s_gn[m][j - 2 * HH] = acci[m]; }
    }
    __syncthreads();
    for (int idx = tid; idx < MA * HH; idx += TA) {
      const int m = idx / HH, i = idx % HH;
      const float r = sigmoidf_(s_g[m][i]);
      const float z = sigmoidf_(s_g[m][HH + i]);
      const float n = tanhf(s_gn[m][i] + r * s_g[m][2 * HH + i]);
      s_h[m][i] = (1.f - z) * n + z * s_h[m][i];
    }
    __syncthreads();
  }

  for (int idx = tid; idx < MA * HH; idx += TA) {
    const int m = idx / HH, i = idx % HH;
    const int q = q0 + m;
    out[q * HH + i] = s_h[m][i];
  }
}

// ---------------- loss kernel: recompute 400 sampled sequences ----------------
__global__ __launch_bounds__(TA) void k_rum_loss(
    const float* __restrict__ hfeat, const float* __restrict__ y0,
    const float* __restrict__ Wih_w, const float* __restrict__ Whh_w,
    const float* __restrict__ bih_w, const float* __restrict__ bhh_w,
    const float* __restrict__ Wih,   const float* __restrict__ Whh,
    const float* __restrict__ bih,   const float* __restrict__ bhh,
    const float* __restrict__ W_ss,  const float* __restrict__ b_ss,
    const int* __restrict__ walks, const int* __restrict__ idxs,
    float* __restrict__ ws)
{
  __shared__ float s_h[MB][HH];
  __shared__ float s_g[MB][GG];
  __shared__ float s_gn[MB][HH];
  __shared__ float s_x[MB][HH];
  __shared__ float s_yw[MB][LL][HH];
  __shared__ int s_wf[MB][LL];
  __shared__ int s_uf[MB][LL];
  __shared__ float s_red[3][TA];

  const int tid = threadIdx.x;
  const int j = tid;
  const int q0 = blockIdx.x * MB;

  if (tid < MB) {
    const int m = tid;
    const int q2 = q0 + m;                 // [0,400)
    const int s  = q2 / SUBN;
    const int node = idxs[q2 % SUBN];
    const int q = s * NN + node;
    int w[LL];
    #pragma unroll
    for (int l = 0; l < LL; ++l) w[l] = walks[q * LL + l];
    #pragma unroll
    for (int l = 0; l < LL; ++l) {
      int u = l;
      #pragma unroll
      for (int l2 = LL - 1; l2 >= 0; --l2) if (w[l2] == w[l]) u = l2;
      s_wf[m][LL - 1 - l] = w[l];
      s_uf[m][LL - 1 - l] = u;
    }
  }
  for (int idx = tid; idx < MB * HH; idx += TA) ((float*)s_h)[idx] = 0.f;
  __syncthreads();

  for (int t = 0; t < LL; ++t) {
    {
      float acc[MB];
      dotsM<MB, true>(Whh_w, j * HH, bhh_w[j], &s_h[0][0], HH, acc);
      #pragma unroll
      for (int m = 0; m < MB; ++m) s_g[m][j] = acc[m];
    }
    __syncthreads();
    for (int idx = tid; idx < MB * HH; idx += TA) {
      const int m = idx / HH, i = idx % HH;
      const int u = s_uf[m][t];
      const float gr = Wih_w[i * LL + u]            + bih_w[i];
      const float gz = Wih_w[(HH + i) * LL + u]     + bih_w[HH + i];
      const float gn = Wih_w[(2 * HH + i) * LL + u] + bih_w[2 * HH + i];
      const float r = sigmoidf_(gr + s_g[m][i]);
      const float z = sigmoidf_(gz + s_g[m][HH + i]);
      const float n = tanhf(gn + r * s_g[m][2 * HH + i]);
      const float hn = (1.f - z) * n + z * s_h[m][i];
      s_h[m][i] = hn;
      s_yw[m][t][i] = hn;
    }
    __syncthreads();
  }

  float pA = 0.f, pB = 0.f, pS = 0.f;

  for (int t = 0; t < LL - 1; ++t) {
    for (int idx = tid; idx < MB * HH; idx += TA) {
      const int m = idx / HH, i = idx % HH;
      s_x[m][i] = hfeat[s_wf[m][t] * HH + i];
    }
    float accg[MB];
    dotsM<MB, true>(Whh, j * HH, bhh[j], &s_h[0][0], HH, accg);
    __syncthreads();
    float acci[MB];
    dotsM<MB, true>(Wih, j * (2 * HH), bih[j], &s_x[0][0], HH, acci);
    dotsM<MB, false>(Wih, j * (2 * HH) + HH, 0.f, &s_yw[0][t][0], LL * HH, acci);
    if (j < 2 * HH) {
      #pragma unroll
      for (int m = 0; m < MB; ++m) s_g[m][j] = accg[m] + acci[m];
    } else {
      #pragma unroll
      for (int m = 0; m < MB; ++m) { s_g[m][j] = accg[m]; s_gn[m][j - 2 * HH] = acci[m]; }
    }
    __syncthreads();
    for (int idx = tid; idx < MB * HH; idx += TA) {
      const int m = idx / HH, i = idx % HH;
      const float r = sigmoidf_(s_g[m][i]);
      const float z = sigmoidf_(s_g[m][HH + i]);
      const float n = tanhf(s_gn[m][i] + r * s_g[m][2 * HH + i]);
      s_h[m][i] = (1.f - z) * n + z * s_h[m][i];
    }
    __syncthreads();

    // y_hat = h_t @ W_ss^T + b_ss ; BCE partial sums.
    // MB*ORIGF = 512 > TA, so this must be a strided loop.
    for (int idx = tid; idx < MB * ORIGF; idx += TA) {
      const int m = idx / ORIGF, o = idx % ORIGF;
      float acc = b_ss[o];
      #pragma unroll 1
      for (int kc = 0; kc < HH; kc += 8) {
        const float4 wa = *(const float4*)(W_ss + o * HH + kc);
        const float4 wb = *(const float4*)(W_ss + o * HH + kc + 4);
        const float4 a = *(const float4*)(&s_h[m][kc]);
        const float4 b = *(const float4*)(&s_h[m][kc + 4]);
        acc = fmaf(wa.x, a.x, acc); acc = fmaf(wa.y, a.y, acc);
        acc = fmaf(wa.z, a.z, acc); acc = fmaf(wa.w, a.w, acc);
        acc = fmaf(wb.x, b.x, acc); acc = fmaf(wb.y, b.y, acc);
        acc = fmaf(wb.z, b.z, acc); acc = fmaf(wb.w, b.w, acc);
      }
      const float yt = y0[s_wf[m][t + 1] * ORIGF + o];
      pA += yt * softplusf_(-acc);
      pB += (1.f - yt) * softplusf_(acc);
      pS += yt;
    }
    __syncthreads();
  }

  s_red[0][tid] = pA; s_red[1][tid] = pB; s_red[2][tid] = pS;
  __syncthreads();
  if (tid == 0) {
    float a = 0.f, b = 0.f, c = 0.f;
    for (int k = 0; k < TA; ++k) { a += s_red[0][k]; b += s_red[1][k]; c += s_red[2][k]; }
    atomicAdd(&ws[1], a);
    atomicAdd(&ws[2], b);
    atomicAdd(&ws[3], c);
  }
}

__global__ void k_zero(float* ws) {
  if (threadIdx.x < 4) ws[threadIdx.x] = 0.f;
}

__global__ void k_final(const float* __restrict__ ws, float* __restrict__ out) {
  if (threadIdx.x == 0) {
    const float cnt = (float)(SSS * SUBN * (LL - 1) * ORIGF);  // 179200
    const float pos_w = cnt / ws[3];
    const float loss = (pos_w * ws[1] + ws[2]) / cnt;
    out[NSEQ * HH] = loss;
  }
}

extern "C" void kernel_launch(void* const* d_in, const int* in_sizes, int n_in,
                              void* d_out, int out_size, void* d_ws, size_t ws_size,
                              hipStream_t stream) {
  const float* hfeat = (const float*)d_in[0];
  const float* y0    = (const float*)d_in[1];
  const float* Wih_w = (const float*)d_in[2];
  const float* Whh_w = (const float*)d_in[3];
  const float* bih_w = (const float*)d_in[4];
  const float* bhh_w = (const float*)d_in[5];
  const float* Wih   = (const float*)d_in[6];
  const float* Whh   = (const float*)d_in[7];
  const float* bih   = (const float*)d_in[8];
  const float* bhh   = (const float*)d_in[9];
  const float* W_ss  = (const float*)d_in[10];
  const float* b_ss  = (const float*)d_in[11];
  const int* walks = (const int*)d_in[12];
  const int* idxs  = (const int*)d_in[13];
  float* out = (float*)d_out;
  float* ws = (float*)d_ws;

  k_zero<<<1, 64, 0, stream>>>(ws);

  const int gridA = NSEQ / MA;              // 5000, exact
  k_rum_main<<<gridA, TA, 0, stream>>>(hfeat, Wih_w, Whh_w, bih_w, bhh_w,
                                       Wih, Whh, bih, bhh, walks, out);

  const int gridB = (SSS * SUBN) / MB;      // 50, exact
  k_rum_loss<<<gridB, TA, 0, stream>>>(hfeat, y0, Wih_w, Whh_w, bih_w, bhh_w,
                                       Wih, Whh, bih, bhh, W_ss, b_ss,
                                       walks, idxs, ws);

  k_final<<<1, 64, 0, stream>>>(ws, out);
}